// Round 8
// baseline (331.886 us; speedup 1.0000x reference)
//
#include <hip/hip_runtime.h>
#include <math.h>

#define BATCH 8
#define NN 2048
#define DIN 256
#define RANK 64
#define TOPKK 32
#define CANDMAX 96
#define RB 16   // rows per fused block

static constexpr size_t A_ELEMS = (size_t)BATCH * NN * NN;   // 33554432
static constexpr size_t S_OFF   = A_ELEMS;
static constexpr size_t R_OFF   = 2 * A_ELEMS;
static constexpr size_t NROWS   = (size_t)BATCH * NN;        // 16384

// ws layout (float offsets) — all fully rewritten every launch (no stale state)
static constexpr size_t G_OFF   = 0;                          // G[8][4096]
static constexpr size_t U_OFF   = 32768;                      // u[8][64]
static constexpr size_t GP_OFF  = 33280;                      // Gpart[64][4160]
static constexpr size_t TAU_OFF = GP_OFF + 64 * 4160;         // tau[16384]
static constexpr size_t T_OFF   = TAU_OFF + NROWS;            // T[16384][64]
// total ≈ 1.36M floats ≈ 5.5 MB

#define NEG_INF (-__builtin_inff())

// ---------------- threefry2x32, JAX partitionable counter-mode (verified r3) ----------------
__device__ __forceinline__ unsigned rotl32(unsigned x, int d) {
  return (x << d) | (x >> (32 - d));
}

__device__ unsigned threefry_bits(unsigned flat) {
  const unsigned ks0 = 0u, ks1 = 42u, ks2 = 0u ^ 42u ^ 0x1BD11BDAu;
  unsigned x0 = 0u + ks0;
  unsigned x1 = flat + ks1;
#define TF_ROUND(r) { x0 += x1; x1 = rotl32(x1, r); x1 ^= x0; }
  TF_ROUND(13) TF_ROUND(15) TF_ROUND(26) TF_ROUND(6)
  x0 += ks1; x1 += ks2 + 1u;
  TF_ROUND(17) TF_ROUND(29) TF_ROUND(16) TF_ROUND(24)
  x0 += ks2; x1 += ks0 + 2u;
  TF_ROUND(13) TF_ROUND(15) TF_ROUND(26) TF_ROUND(6)
  x0 += ks0; x1 += ks1 + 3u;
  TF_ROUND(17) TF_ROUND(29) TF_ROUND(16) TF_ROUND(24)
  x0 += ks1; x1 += ks2 + 4u;
  TF_ROUND(13) TF_ROUND(15) TF_ROUND(26) TF_ROUND(6)
  x0 += ks2; x1 += ks0 + 5u;
#undef TF_ROUND
  return x0 ^ x1;
}

__device__ __forceinline__ unsigned long long make_key(float v, int col) {
  unsigned u = __float_as_uint(v);
  u = (u & 0x80000000u) ? ~u : (u | 0x80000000u);
  return ((unsigned long long)u << 32) | (unsigned)(~col);
}

__device__ __forceinline__ void decode_key(unsigned long long key, float& val, int& col) {
  unsigned hi = (unsigned)(key >> 32);
  unsigned ub = (hi & 0x80000000u) ? (hi ^ 0x80000000u) : ~hi;
  val = __uint_as_float(ub);
  col = (int)(~(unsigned)key) & (NN - 1);
}

// lane MUST be the within-wave lane id (threadIdx.x & 63) (r5 bug)
__device__ __forceinline__ void bitonic64_desc(unsigned long long& key, int lane) {
#pragma unroll
  for (int k = 2; k <= 64; k <<= 1) {
#pragma unroll
    for (int j = k >> 1; j >= 1; j >>= 1) {
      unsigned long long o = __shfl_xor(key, j, 64);
      bool lower = (lane & j) == 0;
      bool desc  = (lane & k) == 0;
      bool takeMax = (lower == desc);
      bool kgo = key > o;
      key = (takeMax == kgo) ? key : o;
    }
  }
}

// ---------------- kernel 1: R = X*W -> out; T = (R*B)/8 -> ws (verified r4; T dest moved) ----------------
__global__ __launch_bounds__(256) void rt_kernel(const float* __restrict__ X,
                                                 const float* __restrict__ W,
                                                 const float* __restrict__ Bm,
                                                 float* __restrict__ out,
                                                 float* __restrict__ ws) {
  __shared__ float Xs[32][256];
  __shared__ float Bs[64][64];
  __shared__ float Rs[32][64];
  const int t = threadIdx.x;
  const int blk = blockIdx.x;
  const int b  = blk >> 6;
  const int rb = blk & 63;
  const float* Xb = X + ((size_t)b * NN + (size_t)rb * 32) * DIN;

#pragma unroll
  for (int it = 0; it < 8; ++it) {
    int flat = it * 1024 + t * 4;
    *(float4*)&Xs[flat >> 8][flat & 255] = *(const float4*)(Xb + flat);
  }
#pragma unroll
  for (int it = 0; it < 4; ++it) {
    int flat = it * 1024 + t * 4;
    *(float4*)&Bs[flat >> 6][flat & 63] = *(const float4*)(Bm + flat);
  }
  __syncthreads();

  const int j = t & 63, rg = t >> 6;
  float acc[8] = {0.f, 0.f, 0.f, 0.f, 0.f, 0.f, 0.f, 0.f};
  for (int k = 0; k < DIN; k += 4) {
    float w0 = W[(k + 0) * RANK + j];
    float w1 = W[(k + 1) * RANK + j];
    float w2 = W[(k + 2) * RANK + j];
    float w3 = W[(k + 3) * RANK + j];
#pragma unroll
    for (int ii = 0; ii < 8; ++ii) {
      float4 xv = *(const float4*)&Xs[rg * 8 + ii][k];
      acc[ii] += xv.x * w0 + xv.y * w1 + xv.z * w2 + xv.w * w3;
    }
  }
  const size_t grow0 = (size_t)b * NN + (size_t)rb * 32;
  float* Rout = out + R_OFF + grow0 * RANK;
#pragma unroll
  for (int ii = 0; ii < 8; ++ii) {
    Rout[(size_t)(rg * 8 + ii) * RANK + j] = acc[ii];
    Rs[rg * 8 + ii][j] = acc[ii];
  }
  __syncthreads();

  float acc2[8] = {0.f, 0.f, 0.f, 0.f, 0.f, 0.f, 0.f, 0.f};
  for (int r = 0; r < RANK; r += 4) {
    float b0 = Bs[r + 0][j];
    float b1 = Bs[r + 1][j];
    float b2 = Bs[r + 2][j];
    float b3 = Bs[r + 3][j];
#pragma unroll
    for (int ii = 0; ii < 8; ++ii) {
      float4 rv = *(const float4*)&Rs[rg * 8 + ii][r];
      acc2[ii] += rv.x * b0 + rv.y * b1 + rv.z * b2 + rv.w * b3;
    }
  }
  float* Tout = ws + T_OFF + grow0 * RANK;   // T scratch now in ws (no A-region alias)
#pragma unroll
  for (int ii = 0; ii < 8; ++ii)
    Tout[(size_t)(rg * 8 + ii) * RANK + j] = acc2[ii] * 0.125f;
}

// ---------------- kernel 2a: partial G = R^T R, u = sum rows (verified r7) ----------------
__global__ __launch_bounds__(256) void ga_kernel(const float* __restrict__ out,
                                                 float* __restrict__ ws) {
  __shared__ float Rl[128][68];
  const int t = threadIdx.x;
  const int b = blockIdx.x >> 3, chunk = blockIdx.x & 7;
  const float* Rb = out + R_OFF + ((size_t)b * NN + (size_t)chunk * 256) * RANK;
  const int i0 = (t >> 4) * 4, j0 = (t & 15) * 4;
  float acc[4][4];
#pragma unroll
  for (int a = 0; a < 4; ++a)
#pragma unroll
    for (int c = 0; c < 4; ++c) acc[a][c] = 0.f;
  float uacc = 0.f;

  for (int s2 = 0; s2 < 2; ++s2) {
    const float* src = Rb + (size_t)s2 * 128 * RANK;
#pragma unroll
    for (int it = 0; it < 8; ++it) {
      int flat = it * 1024 + t * 4;
      *(float4*)&Rl[flat >> 6][flat & 63] = *(const float4*)(src + flat);
    }
    __syncthreads();
    for (int r = 0; r < 128; ++r) {
      float4 a = *(const float4*)&Rl[r][i0];
      float4 bb = *(const float4*)&Rl[r][j0];
      acc[0][0] = fmaf(a.x, bb.x, acc[0][0]); acc[0][1] = fmaf(a.x, bb.y, acc[0][1]);
      acc[0][2] = fmaf(a.x, bb.z, acc[0][2]); acc[0][3] = fmaf(a.x, bb.w, acc[0][3]);
      acc[1][0] = fmaf(a.y, bb.x, acc[1][0]); acc[1][1] = fmaf(a.y, bb.y, acc[1][1]);
      acc[1][2] = fmaf(a.y, bb.z, acc[1][2]); acc[1][3] = fmaf(a.y, bb.w, acc[1][3]);
      acc[2][0] = fmaf(a.z, bb.x, acc[2][0]); acc[2][1] = fmaf(a.z, bb.y, acc[2][1]);
      acc[2][2] = fmaf(a.z, bb.z, acc[2][2]); acc[2][3] = fmaf(a.z, bb.w, acc[2][3]);
      acc[3][0] = fmaf(a.w, bb.x, acc[3][0]); acc[3][1] = fmaf(a.w, bb.y, acc[3][1]);
      acc[3][2] = fmaf(a.w, bb.z, acc[3][2]); acc[3][3] = fmaf(a.w, bb.w, acc[3][3]);
    }
    if (t < 64) {
      for (int r = 0; r < 128; ++r) uacc += Rl[r][t];
    }
    __syncthreads();
  }
  float* dst = ws + GP_OFF + (size_t)blockIdx.x * 4160;
#pragma unroll
  for (int a = 0; a < 4; ++a) {
    float4 f = make_float4(acc[a][0], acc[a][1], acc[a][2], acc[a][3]);
    *(float4*)&dst[(i0 + a) * 64 + j0] = f;
  }
  if (t < 64) dst[4096 + t] = uacc;
}

// ---------------- kernel 2b: deterministic reduction of G/u partials (verified r7) ----------------
__global__ __launch_bounds__(256) void gb_kernel(float* __restrict__ ws) {
  const int b = blockIdx.x, t = threadIdx.x;
  for (int idx = t; idx < 4160; idx += 256) {
    float s = 0.f;
    for (int c = 0; c < 8; ++c)
      s += ws[GP_OFF + (size_t)(b * 8 + c) * 4160 + idx];
    if (idx < 4096) ws[G_OFF + (size_t)b * 4096 + idx] = s;
    else            ws[U_OFF + (size_t)b * 64 + (idx - 4096)] = s;
  }
}

// ---------------- kernel 2c: per-row tau = mu + z*sigma (verified r7; T from ws) ----------------
__global__ __launch_bounds__(256) void tau_kernel(float* __restrict__ ws) {
  const int t = threadIdx.x, wv = t >> 6, lane = t & 63;
  const int g = blockIdx.x * 4 + wv;
  const int b = g >> 11;
  const float* Gb = ws + G_OFF + (size_t)b * 4096;
  float tl = ws[T_OFF + (size_t)g * RANK + lane];
  float ul = ws[U_OFF + (size_t)b * 64 + lane];
  float gj = 0.f;
  for (int k = 0; k < 64; ++k) {
    float tk = __shfl(tl, k, 64);
    gj = fmaf(tk, Gb[k * 64 + lane], gj);
  }
  float qq = gj * tl;
  float mua = tl * ul;
#pragma unroll
  for (int off = 1; off < 64; off <<= 1) {
    qq  += __shfl_xor(qq, off, 64);
    mua += __shfl_xor(mua, off, 64);
  }
  float ms = qq * (1.f / 2048.f);
  float mu = mua * (1.f / 2048.f);
  float sigma = sqrtf(fmaxf(ms - mu * mu, 1e-12f));
  if (lane == 0)
    ws[TAU_OFF + g] = mu + 1.8627f * sigma;   // target ~64 candidates (r6/r7-tested)
}

// ---------------- kernel 3: FUSED S-GEMM + LDS screen + sort + softmax/dropout -> S, A ----------------
__global__ __launch_bounds__(256) void fused_kernel(float* __restrict__ out,
                                                    const float* __restrict__ ws) {
  __shared__ float Tk[64][RB];                    // 4 KB, k-major T
  __shared__ float tau_l[RB];
  __shared__ int   cnt_l[RB];
  __shared__ unsigned long long cand[RB][CANDMAX];// 12 KB
  __shared__ float arena[8192];                   // 32 KB: Rk[64][128] | rowbuf 4x2048

  const int t = threadIdx.x;
  const int b = blockIdx.x >> 7;
  const int rblk = blockIdx.x & 127;
  const int n0 = rblk * RB;
  const size_t g0 = (size_t)b * NN + n0;

  // stage T k-major (once)
  {
    int t4 = t * 4, r = t4 >> 6, k0 = t4 & 63;
    float4 f = *(const float4*)(ws + T_OFF + (g0 + r) * RANK + k0);
    Tk[k0 + 0][r] = f.x; Tk[k0 + 1][r] = f.y;
    Tk[k0 + 2][r] = f.z; Tk[k0 + 3][r] = f.w;
  }
  if (t < RB) { tau_l[t] = ws[TAU_OFF + g0 + t]; cnt_l[t] = 0; }
  __syncthreads();

  const float* Rsrc = out + R_OFF + (size_t)b * NN * RANK;
  float* Sb = out + S_OFF + (size_t)b * NN * NN;
  float* Rk = arena;                               // [64][128] k-major

  const int tx = t & 31, ty = t >> 5;
  const int r0 = ty * 2, r1 = r0 + 1;
  const float tau0 = tau_l[r0], tau1 = tau_l[r1];
  const int cstage = t & 127;                      // staging col in tile
  const int khalf = (t >> 7) * 32;                 // staging k half

  for (int tile = 0; tile < 16; ++tile) {
    // stage Rk: cols [tile*128, +128), k-major; conflict-free writes (bank = c%32, 2-way)
    {
      const float* src = Rsrc + (size_t)(tile * 128 + cstage) * RANK + khalf;
#pragma unroll
      for (int q = 0; q < 8; ++q) {
        float4 f = *(const float4*)(src + q * 4);
        int kk = khalf + q * 4;
        Rk[(kk + 0) * 128 + cstage] = f.x;
        Rk[(kk + 1) * 128 + cstage] = f.y;
        Rk[(kk + 2) * 128 + cstage] = f.z;
        Rk[(kk + 3) * 128 + cstage] = f.w;
      }
    }
    __syncthreads();

    float4 a0 = make_float4(0.f, 0.f, 0.f, 0.f);
    float4 a1 = make_float4(0.f, 0.f, 0.f, 0.f);
#pragma unroll 8
    for (int k = 0; k < 64; ++k) {
      float t0 = Tk[k][r0];                        // broadcast reads
      float t1 = Tk[k][r1];
      float4 bb = *(const float4*)&Rk[k * 128 + tx * 4];
      a0.x = fmaf(t0, bb.x, a0.x); a0.y = fmaf(t0, bb.y, a0.y);
      a0.z = fmaf(t0, bb.z, a0.z); a0.w = fmaf(t0, bb.w, a0.w);
      a1.x = fmaf(t1, bb.x, a1.x); a1.y = fmaf(t1, bb.y, a1.y);
      a1.z = fmaf(t1, bb.z, a1.z); a1.w = fmaf(t1, bb.w, a1.w);
    }

    const int mbase = tile * 128 + tx * 4;
    *(float4*)(Sb + (size_t)(n0 + r0) * NN + mbase) = a0;
    *(float4*)(Sb + (size_t)(n0 + r1) * NN + mbase) = a1;

#define SCR(RL, NA, TAU, V, M)                                        \
    if ((M) != (NA) && (V) > (TAU)) {                                 \
      int pos = atomicAdd(&cnt_l[RL], 1);                             \
      if (pos < CANDMAX) cand[RL][pos] = make_key((V), (M));          \
    }
    SCR(r0, n0 + r0, tau0, a0.x, mbase + 0)
    SCR(r0, n0 + r0, tau0, a0.y, mbase + 1)
    SCR(r0, n0 + r0, tau0, a0.z, mbase + 2)
    SCR(r0, n0 + r0, tau0, a0.w, mbase + 3)
    SCR(r1, n0 + r1, tau1, a1.x, mbase + 0)
    SCR(r1, n0 + r1, tau1, a1.y, mbase + 1)
    SCR(r1, n0 + r1, tau1, a1.z, mbase + 2)
    SCR(r1, n0 + r1, tau1, a1.w, mbase + 3)
#undef SCR
    __syncthreads();                               // protect Rk before next stage
  }

  // -------- epilogue: 4 waves x 4 rounds; rowbuf reuses arena (Rk dead) --------
  const int wv = t >> 6, lane = t & 63;
  float* rowbuf = arena + wv * 2048;

  for (int round = 0; round < 4; ++round) {
    const int rl = wv * 4 + round;
    const int g = (int)g0 + rl;
    const int n = n0 + rl;
    const int c = cnt_l[rl];

    unsigned long long key = 0ull;
    if (c >= TOPKK && c <= CANDMAX) {
      if (c <= 64) {
        key = (lane < c) ? cand[rl][lane] : 0ull;
        bitonic64_desc(key, lane);
      } else {
        key = cand[rl][lane];
        bitonic64_desc(key, lane);
        if (lane >= 32) { int idx = 64 + (lane - 32); key = (idx < c) ? cand[rl][idx] : 0ull; }
        bitonic64_desc(key, lane);
      }
    } else {
      // ---- rare fallback: exact re-screen of this block's own S row (r4/r7-verified) ----
      const float* row = Sb + (size_t)n * NN;
      float v[32];
#pragma unroll
      for (int jj = 0; jj < 8; ++jj) {
        float4 f = *(const float4*)(row + jj * 256 + lane * 4);
        v[jj * 4 + 0] = f.x; v[jj * 4 + 1] = f.y;
        v[jj * 4 + 2] = f.z; v[jj * 4 + 3] = f.w;
      }
      float s = 0.f, ss = 0.f;
#pragma unroll
      for (int jj = 0; jj < 32; ++jj) { s += v[jj]; ss = fmaf(v[jj], v[jj], ss); }
#pragma unroll
      for (int off = 1; off < 64; off <<= 1) {
        s += __shfl_xor(s, off, 64); ss += __shfl_xor(ss, off, 64);
      }
      const float mu = s * (1.f / 2048.f);
      const float sigma = sqrtf(fmaxf(ss * (1.f / 2048.f) - mu * mu, 1e-12f));
      {
        int d = n - lane * 4;
        if (d >= 0 && d < NN && (d & 255) < 4) v[((d >> 8) << 2) | (d & 3)] = NEG_INF;
      }
      float tau = mu + 2.0641f * sigma;
      float lo_b = -3.0e38f, hi_b = 3.0e38f;
      float step = sigma + 1e-20f;
      bool found = false;
      for (int it = 0; it < 40; ++it) {
        int cl = 0;
#pragma unroll
        for (int jj = 0; jj < 32; ++jj) cl += (v[jj] > tau) ? 1 : 0;
#pragma unroll
        for (int off = 1; off < 64; off <<= 1) cl += __shfl_xor(cl, off, 64);
        if (cl >= TOPKK && cl <= 64) { found = true; break; }
        if (cl > 64) lo_b = fmaxf(lo_b, tau); else hi_b = fminf(hi_b, tau);
        float tn = 0.f; bool ok = false;
        if (it < 6) {
          float pp = fminf(fmaxf((float)cl, 1.f) * (1.f / 2048.f), 0.5f);
          float tt = sqrtf(-2.f * logf(pp));
          float zc = tt - (2.30753f + 0.27061f * tt) /
                          (1.f + tt * (0.99229f + 0.04481f * tt));
          zc = fmaxf(zc, 0.05f);
          tn = mu + 2.0641f * ((tau - mu) / zc);
          ok = (tn > lo_b && tn < hi_b);
        }
        if (!ok) {
          if (lo_b > -1.0e38f && hi_b < 1.0e38f) tn = 0.5f * lo_b + 0.5f * hi_b;
          else if (cl > 64) { tn = tau + step; step *= 2.f; }
          else              { tn = tau - step; step *= 2.f; }
        }
        tau = tn;
      }
      if (found) {
        // wave-private compaction via shuffle prefix (no LDS needed)
        int mycnt = 0;
#pragma unroll
        for (int jj = 0; jj < 32; ++jj) mycnt += (v[jj] > tau) ? 1 : 0;
        int pre = mycnt;
#pragma unroll
        for (int off = 1; off < 64; off <<= 1) {
          int o = __shfl_up(pre, off, 64);
          if (lane >= off) pre += o;
        }
        int base = pre - mycnt;                 // exclusive prefix
        int tot = __shfl(pre, 63, 64);
        // serialize this wave's winners into lanes via repeated extraction:
        // simpler: each lane pushes winners into its slots [base, base+mycnt) of a
        // temporary in cand[rl] (safe: c<32 or c>CANDMAX means cand row unusable anyway,
        // and cnt_l is not re-read)
        {
          int pos = base;
#pragma unroll
          for (int jj = 0; jj < 32; ++jj) {
            if (v[jj] > tau) {
              int col = ((jj >> 2) << 8) + lane * 4 + (jj & 3);
              if (pos < CANDMAX) cand[rl][pos] = make_key(v[jj], col);
              ++pos;
            }
          }
        }
        __builtin_amdgcn_s_waitcnt(0);          // drain LDS (lgkmcnt) before re-read
        key = (lane < tot && lane < CANDMAX) ? cand[rl][lane] : 0ull;
        bitonic64_desc(key, lane);
      } else {
        unsigned alive = 0xFFFFFFFFu;
        unsigned long long keysel = 0ull;
        for (int it = 0; it < TOPKK; ++it) {
          unsigned long long best = 0ull;
#pragma unroll
          for (int jj = 0; jj < 32; ++jj) {
            if ((alive >> jj) & 1u) {
              int col = ((jj >> 2) << 8) + lane * 4 + (jj & 3);
              unsigned long long kk = make_key(v[jj], col);
              if (kk > best) best = kk;
            }
          }
          unsigned long long b2 = best;
#pragma unroll
          for (int off = 1; off < 64; off <<= 1) {
            unsigned long long o = __shfl_xor(b2, off, 64);
            if (o > b2) b2 = o;
          }
          if (lane == it) keysel = b2;
          if (best == b2) {
#pragma unroll
            for (int jj = 0; jj < 32; ++jj) {
              int col = ((jj >> 2) << 8) + lane * 4 + (jj & 3);
              if (make_key(v[jj], col) == b2) alive &= ~(1u << jj);
            }
          }
        }
        key = keysel;
      }
    }

    // ---- softmax + dropout + renorm (r4/r7-verified) ----
    float val; int col;
    decode_key(key, val, col);
    float m = __shfl(val, 0, 64);
    float e = (lane < TOPKK) ? expf(val - m) : 0.f;
    float s1 = e;
#pragma unroll
    for (int off = 1; off < 64; off <<= 1) s1 += __shfl_xor(s1, off, 64);
    float a1v = e / fmaxf(s1, 1e-6f);

    float a2 = 0.f;
    if (lane < TOPKK) {
      unsigned flat = (unsigned)g * 2048u + (unsigned)col;
      unsigned bits = threefry_bits(flat);
      float u = __uint_as_float((bits >> 9) | 0x3f800000u) - 1.0f;
      if (u <= 0.9f) a2 = a1v * (1.f / 0.9f);
    }
    float s2 = a2;
#pragma unroll
    for (int off = 1; off < 64; off <<= 1) s2 += __shfl_xor(s2, off, 64);
    float av = a2 / fmaxf(s2, 1e-6f);

    // ---- materialize A row via LDS rowbuf (r4-verified path) ----
#pragma unroll
    for (int jj = 0; jj < 8; ++jj)
      *(float4*)&rowbuf[jj * 256 + lane * 4] = make_float4(0.f, 0.f, 0.f, 0.f);
    __syncthreads();
    if (lane < TOPKK) rowbuf[col] = av;
    __syncthreads();
    float* Arow = out + (size_t)g * NN;
#pragma unroll
    for (int jj = 0; jj < 8; ++jj)
      *(float4*)(Arow + jj * 256 + lane * 4) = *(float4*)&rowbuf[jj * 256 + lane * 4];
  }
}

extern "C" void kernel_launch(void* const* d_in, const int* in_sizes, int n_in,
                              void* d_out, int out_size, void* d_ws, size_t ws_size,
                              hipStream_t stream) {
  const float* X  = (const float*)d_in[0];
  const float* W  = (const float*)d_in[1];
  const float* Bm = (const float*)d_in[2];
  float* out = (float*)d_out;
  float* ws  = (float*)d_ws;   // ~5.5 MB used

  hipLaunchKernelGGL(rt_kernel, dim3(512), dim3(256), 0, stream, X, W, Bm, out, ws);
  hipLaunchKernelGGL(ga_kernel, dim3(64), dim3(256), 0, stream, out, ws);
  hipLaunchKernelGGL(gb_kernel, dim3(8), dim3(256), 0, stream, ws);
  hipLaunchKernelGGL(tau_kernel, dim3(4096), dim3(256), 0, stream, ws);
  hipLaunchKernelGGL(fused_kernel, dim3(1024), dim3(256), 0, stream, out, ws);
}

// Round 9
// 199.026 us; speedup vs baseline: 1.6675x; 1.6675x over previous
//
#include <hip/hip_runtime.h>
#include <math.h>

#define BATCH 8
#define NN 2048
#define DIN 256
#define RANK 64
#define TOPKK 32
#define CANDMAX 96

static constexpr size_t A_ELEMS = (size_t)BATCH * NN * NN;   // 33554432
static constexpr size_t S_OFF   = A_ELEMS;
static constexpr size_t R_OFF   = 2 * A_ELEMS;
static constexpr size_t NROWS   = (size_t)BATCH * NN;        // 16384

// ws layout (float offsets) — fully rewritten every launch
static constexpr size_t G_OFF   = 0;                          // G[8][4096]
static constexpr size_t U_OFF   = 32768;                      // u[8][64]
static constexpr size_t GP_OFF  = 33280;                      // Gpart[64][4160]
static constexpr size_t TAU_OFF = GP_OFF + 64 * 4160;         // tau[16384]
static constexpr size_t T_OFF   = TAU_OFF + NROWS;            // T[16384][64]
// total ≈ 5.5 MB

#define NEG_INF (-__builtin_inff())

// ---------------- threefry2x32, JAX partitionable counter-mode (verified r3) ----------------
__device__ __forceinline__ unsigned rotl32(unsigned x, int d) {
  return (x << d) | (x >> (32 - d));
}

__device__ unsigned threefry_bits(unsigned flat) {
  const unsigned ks0 = 0u, ks1 = 42u, ks2 = 0u ^ 42u ^ 0x1BD11BDAu;
  unsigned x0 = 0u + ks0;
  unsigned x1 = flat + ks1;
#define TF_ROUND(r) { x0 += x1; x1 = rotl32(x1, r); x1 ^= x0; }
  TF_ROUND(13) TF_ROUND(15) TF_ROUND(26) TF_ROUND(6)
  x0 += ks1; x1 += ks2 + 1u;
  TF_ROUND(17) TF_ROUND(29) TF_ROUND(16) TF_ROUND(24)
  x0 += ks2; x1 += ks0 + 2u;
  TF_ROUND(13) TF_ROUND(15) TF_ROUND(26) TF_ROUND(6)
  x0 += ks0; x1 += ks1 + 3u;
  TF_ROUND(17) TF_ROUND(29) TF_ROUND(16) TF_ROUND(24)
  x0 += ks1; x1 += ks2 + 4u;
  TF_ROUND(13) TF_ROUND(15) TF_ROUND(26) TF_ROUND(6)
  x0 += ks2; x1 += ks0 + 5u;
#undef TF_ROUND
  return x0 ^ x1;
}

__device__ __forceinline__ unsigned long long make_key(float v, int col) {
  unsigned u = __float_as_uint(v);
  u = (u & 0x80000000u) ? ~u : (u | 0x80000000u);
  return ((unsigned long long)u << 32) | (unsigned)(~col);
}

__device__ __forceinline__ void decode_key(unsigned long long key, float& val, int& col) {
  unsigned hi = (unsigned)(key >> 32);
  unsigned ub = (hi & 0x80000000u) ? (hi ^ 0x80000000u) : ~hi;
  val = __uint_as_float(ub);
  col = (int)(~(unsigned)key) & (NN - 1);
}

// lane MUST be the within-wave lane id (threadIdx.x & 63) (r5 bug)
__device__ __forceinline__ void bitonic64_desc(unsigned long long& key, int lane) {
#pragma unroll
  for (int k = 2; k <= 64; k <<= 1) {
#pragma unroll
    for (int j = k >> 1; j >= 1; j >>= 1) {
      unsigned long long o = __shfl_xor(key, j, 64);
      bool lower = (lane & j) == 0;
      bool desc  = (lane & k) == 0;
      bool takeMax = (lower == desc);
      bool kgo = key > o;
      key = (takeMax == kgo) ? key : o;
    }
  }
}

// ---------------- kernel 1: R = X*W -> out; T = (R*B)/8 -> ws (verified r4/r8) ----------------
__global__ __launch_bounds__(256) void rt_kernel(const float* __restrict__ X,
                                                 const float* __restrict__ W,
                                                 const float* __restrict__ Bm,
                                                 float* __restrict__ out,
                                                 float* __restrict__ ws) {
  __shared__ float Xs[32][256];
  __shared__ float Bs[64][64];
  __shared__ float Rs[32][64];
  const int t = threadIdx.x;
  const int blk = blockIdx.x;
  const int b  = blk >> 6;
  const int rb = blk & 63;
  const float* Xb = X + ((size_t)b * NN + (size_t)rb * 32) * DIN;

#pragma unroll
  for (int it = 0; it < 8; ++it) {
    int flat = it * 1024 + t * 4;
    *(float4*)&Xs[flat >> 8][flat & 255] = *(const float4*)(Xb + flat);
  }
#pragma unroll
  for (int it = 0; it < 4; ++it) {
    int flat = it * 1024 + t * 4;
    *(float4*)&Bs[flat >> 6][flat & 63] = *(const float4*)(Bm + flat);
  }
  __syncthreads();

  const int j = t & 63, rg = t >> 6;
  float acc[8] = {0.f, 0.f, 0.f, 0.f, 0.f, 0.f, 0.f, 0.f};
  for (int k = 0; k < DIN; k += 4) {
    float w0 = W[(k + 0) * RANK + j];
    float w1 = W[(k + 1) * RANK + j];
    float w2 = W[(k + 2) * RANK + j];
    float w3 = W[(k + 3) * RANK + j];
#pragma unroll
    for (int ii = 0; ii < 8; ++ii) {
      float4 xv = *(const float4*)&Xs[rg * 8 + ii][k];
      acc[ii] += xv.x * w0 + xv.y * w1 + xv.z * w2 + xv.w * w3;
    }
  }
  const size_t grow0 = (size_t)b * NN + (size_t)rb * 32;
  float* Rout = out + R_OFF + grow0 * RANK;
#pragma unroll
  for (int ii = 0; ii < 8; ++ii) {
    Rout[(size_t)(rg * 8 + ii) * RANK + j] = acc[ii];
    Rs[rg * 8 + ii][j] = acc[ii];
  }
  __syncthreads();

  float acc2[8] = {0.f, 0.f, 0.f, 0.f, 0.f, 0.f, 0.f, 0.f};
  for (int r = 0; r < RANK; r += 4) {
    float b0 = Bs[r + 0][j];
    float b1 = Bs[r + 1][j];
    float b2 = Bs[r + 2][j];
    float b3 = Bs[r + 3][j];
#pragma unroll
    for (int ii = 0; ii < 8; ++ii) {
      float4 rv = *(const float4*)&Rs[rg * 8 + ii][r];
      acc2[ii] += rv.x * b0 + rv.y * b1 + rv.z * b2 + rv.w * b3;
    }
  }
  float* Tout = ws + T_OFF + grow0 * RANK;
#pragma unroll
  for (int ii = 0; ii < 8; ++ii)
    Tout[(size_t)(rg * 8 + ii) * RANK + j] = acc2[ii] * 0.125f;
}

// ---------------- kernel 2a: partial G = R^T R, u = sum rows (verified r7/r8) ----------------
__global__ __launch_bounds__(256) void ga_kernel(const float* __restrict__ out,
                                                 float* __restrict__ ws) {
  __shared__ float Rl[128][68];
  const int t = threadIdx.x;
  const int b = blockIdx.x >> 3, chunk = blockIdx.x & 7;
  const float* Rb = out + R_OFF + ((size_t)b * NN + (size_t)chunk * 256) * RANK;
  const int i0 = (t >> 4) * 4, j0 = (t & 15) * 4;
  float acc[4][4];
#pragma unroll
  for (int a = 0; a < 4; ++a)
#pragma unroll
    for (int c = 0; c < 4; ++c) acc[a][c] = 0.f;
  float uacc = 0.f;

  for (int s2 = 0; s2 < 2; ++s2) {
    const float* src = Rb + (size_t)s2 * 128 * RANK;
#pragma unroll
    for (int it = 0; it < 8; ++it) {
      int flat = it * 1024 + t * 4;
      *(float4*)&Rl[flat >> 6][flat & 63] = *(const float4*)(src + flat);
    }
    __syncthreads();
    for (int r = 0; r < 128; ++r) {
      float4 a = *(const float4*)&Rl[r][i0];
      float4 bb = *(const float4*)&Rl[r][j0];
      acc[0][0] = fmaf(a.x, bb.x, acc[0][0]); acc[0][1] = fmaf(a.x, bb.y, acc[0][1]);
      acc[0][2] = fmaf(a.x, bb.z, acc[0][2]); acc[0][3] = fmaf(a.x, bb.w, acc[0][3]);
      acc[1][0] = fmaf(a.y, bb.x, acc[1][0]); acc[1][1] = fmaf(a.y, bb.y, acc[1][1]);
      acc[1][2] = fmaf(a.y, bb.z, acc[1][2]); acc[1][3] = fmaf(a.y, bb.w, acc[1][3]);
      acc[2][0] = fmaf(a.z, bb.x, acc[2][0]); acc[2][1] = fmaf(a.z, bb.y, acc[2][1]);
      acc[2][2] = fmaf(a.z, bb.z, acc[2][2]); acc[2][3] = fmaf(a.z, bb.w, acc[2][3]);
      acc[3][0] = fmaf(a.w, bb.x, acc[3][0]); acc[3][1] = fmaf(a.w, bb.y, acc[3][1]);
      acc[3][2] = fmaf(a.w, bb.z, acc[3][2]); acc[3][3] = fmaf(a.w, bb.w, acc[3][3]);
    }
    if (t < 64) {
      for (int r = 0; r < 128; ++r) uacc += Rl[r][t];
    }
    __syncthreads();
  }
  float* dst = ws + GP_OFF + (size_t)blockIdx.x * 4160;
#pragma unroll
  for (int a = 0; a < 4; ++a) {
    float4 f = make_float4(acc[a][0], acc[a][1], acc[a][2], acc[a][3]);
    *(float4*)&dst[(i0 + a) * 64 + j0] = f;
  }
  if (t < 64) dst[4096 + t] = uacc;
}

// ---------------- kernel 2b: deterministic reduction of G/u partials (verified r7/r8) ----------------
__global__ __launch_bounds__(256) void gb_kernel(float* __restrict__ ws) {
  const int b = blockIdx.x, t = threadIdx.x;
  for (int idx = t; idx < 4160; idx += 256) {
    float s = 0.f;
    for (int c = 0; c < 8; ++c)
      s += ws[GP_OFF + (size_t)(b * 8 + c) * 4160 + idx];
    if (idx < 4096) ws[G_OFF + (size_t)b * 4096 + idx] = s;
    else            ws[U_OFF + (size_t)b * 64 + (idx - 4096)] = s;
  }
}

// ---------------- kernel 2c: per-row tau = mu + z*sigma (verified r7/r8) ----------------
__global__ __launch_bounds__(256) void tau_kernel(float* __restrict__ ws) {
  const int t = threadIdx.x, wv = t >> 6, lane = t & 63;
  const int g = blockIdx.x * 4 + wv;
  const int b = g >> 11;
  const float* Gb = ws + G_OFF + (size_t)b * 4096;
  float tl = ws[T_OFF + (size_t)g * RANK + lane];
  float ul = ws[U_OFF + (size_t)b * 64 + lane];
  float gj = 0.f;
  for (int k = 0; k < 64; ++k) {
    float tk = __shfl(tl, k, 64);
    gj = fmaf(tk, Gb[k * 64 + lane], gj);
  }
  float qq = gj * tl;
  float mua = tl * ul;
#pragma unroll
  for (int off = 1; off < 64; off <<= 1) {
    qq  += __shfl_xor(qq, off, 64);
    mua += __shfl_xor(mua, off, 64);
  }
  float ms = qq * (1.f / 2048.f);
  float mu = mua * (1.f / 2048.f);
  float sigma = sqrtf(fmaxf(ms - mu * mu, 1e-12f));
  if (lane == 0)
    ws[TAU_OFF + g] = mu + 1.8627f * sigma;   // target ~64 candidates
}

// ---------------- kernel 3: S = T * R^T (verified r4 tiling; T from ws) ----------------
__global__ __launch_bounds__(256) void s_kernel(float* __restrict__ out,
                                                const float* __restrict__ ws) {
  __shared__ float Ts[64][68];
  __shared__ float Rs[64][68];
  const int t = threadIdx.x;
  const int bx = blockIdx.x;  // col tile
  const int by = blockIdx.y;  // row tile
  const int bz = blockIdx.z;  // batch
  const float* Tg = ws + T_OFF + ((size_t)bz * NN + (size_t)by * 64) * RANK;
  const float* Rg = out + R_OFF + ((size_t)bz * NN + (size_t)bx * 64) * RANK;

#pragma unroll
  for (int it = 0; it < 4; ++it) {
    int flat = it * 1024 + t * 4;
    int r = flat >> 6, c = flat & 63;
    *(float4*)&Ts[r][c] = *(const float4*)(Tg + flat);
    *(float4*)&Rs[r][c] = *(const float4*)(Rg + flat);
  }
  __syncthreads();

  const int tx = t & 15, ty = t >> 4;
  float acc[4][4];
#pragma unroll
  for (int ii = 0; ii < 4; ++ii)
#pragma unroll
    for (int jj = 0; jj < 4; ++jj) acc[ii][jj] = 0.f;

  for (int k = 0; k < 64; k += 4) {
    float4 a[4], bb[4];
#pragma unroll
    for (int ii = 0; ii < 4; ++ii) a[ii] = *(const float4*)&Ts[ty + 16 * ii][k];
#pragma unroll
    for (int jj = 0; jj < 4; ++jj) bb[jj] = *(const float4*)&Rs[tx + 16 * jj][k];
#pragma unroll
    for (int ii = 0; ii < 4; ++ii)
#pragma unroll
      for (int jj = 0; jj < 4; ++jj)
        acc[ii][jj] += a[ii].x * bb[jj].x + a[ii].y * bb[jj].y +
                       a[ii].z * bb[jj].z + a[ii].w * bb[jj].w;
  }

  float* Sb = out + S_OFF + (size_t)bz * NN * NN;
#pragma unroll
  for (int ii = 0; ii < 4; ++ii) {
    int n = by * 64 + ty + 16 * ii;
#pragma unroll
    for (int jj = 0; jj < 4; ++jj) {
      int m = bx * 64 + tx + 16 * jj;
      Sb[(size_t)n * NN + m] = acc[ii][jj];
    }
  }
}

// ---------------- kernel 4: tau-screen -> bitonic top-32 -> softmax/dropout -> A ----------------
__global__ __launch_bounds__(256) void topk_kernel(float* __restrict__ out,
                                                   const float* __restrict__ ws) {
  __shared__ unsigned long long cand[4][CANDMAX];  // 3 KB
  __shared__ int cnt_l[4];
  __shared__ float rowbuf[4][2048];                // 32 KB
  const int t = threadIdx.x;
  const int wv = t >> 6, lane = t & 63;
  const int g = blockIdx.x * 4 + wv;               // global row
  const int n = g & (NN - 1);

  if (t < 4) cnt_l[t] = 0;
  const float tau = ws[TAU_OFF + g];

  const float* row = out + S_OFF + (size_t)g * NN;
  float v[32];
#pragma unroll
  for (int jj = 0; jj < 8; ++jj) {
    float4 f = *(const float4*)(row + jj * 256 + lane * 4);
    v[jj * 4 + 0] = f.x; v[jj * 4 + 1] = f.y;
    v[jj * 4 + 2] = f.z; v[jj * 4 + 3] = f.w;
  }
  __syncthreads();   // cnt_l ready

  // ---- screen against precomputed tau (common path: no stats, no search) ----
#pragma unroll
  for (int jj = 0; jj < 32; ++jj) {
    int col = ((jj >> 2) << 8) + lane * 4 + (jj & 3);
    if (col != n && v[jj] > tau) {
      int pos = atomicAdd(&cnt_l[wv], 1);
      if (pos < CANDMAX) cand[wv][pos] = make_key(v[jj], col);
    }
  }
  __syncthreads();   // cand ready

  int myc = cnt_l[wv];
  unsigned long long keysel = 0ull;
  if (myc < TOPKK || myc > CANDMAX) {
    // ---- rare fallback: r4-verified stats + threshold search from registers ----
    float s = 0.f, ss = 0.f;
#pragma unroll
    for (int jj = 0; jj < 32; ++jj) { s += v[jj]; ss = fmaf(v[jj], v[jj], ss); }
#pragma unroll
    for (int off = 1; off < 64; off <<= 1) {
      s += __shfl_xor(s, off, 64); ss += __shfl_xor(ss, off, 64);
    }
    const float mu = s * (1.f / 2048.f);
    const float sigma = sqrtf(fmaxf(ss * (1.f / 2048.f) - mu * mu, 1e-12f));
    {
      int d = n - lane * 4;
      if (d >= 0 && d < NN && (d & 255) < 4) v[((d >> 8) << 2) | (d & 3)] = NEG_INF;
    }
    float tau2 = mu + 2.0641f * sigma;
    float lo_b = -3.0e38f, hi_b = 3.0e38f;
    float step = sigma + 1e-20f;
    bool found = false;
    for (int it = 0; it < 40; ++it) {
      int cl = 0;
#pragma unroll
      for (int jj = 0; jj < 32; ++jj) cl += (v[jj] > tau2) ? 1 : 0;
#pragma unroll
      for (int off = 1; off < 64; off <<= 1) cl += __shfl_xor(cl, off, 64);
      if (cl >= TOPKK && cl <= 64) { found = true; break; }
      if (cl > 64) lo_b = fmaxf(lo_b, tau2); else hi_b = fminf(hi_b, tau2);
      float tn = 0.f; bool ok = false;
      if (it < 6) {
        float pp = fminf(fmaxf((float)cl, 1.f) * (1.f / 2048.f), 0.5f);
        float tt = sqrtf(-2.f * logf(pp));
        float zc = tt - (2.30753f + 0.27061f * tt) /
                        (1.f + tt * (0.99229f + 0.04481f * tt));
        zc = fmaxf(zc, 0.05f);
        tn = mu + 2.0641f * ((tau2 - mu) / zc);
        ok = (tn > lo_b && tn < hi_b);
      }
      if (!ok) {
        if (lo_b > -1.0e38f && hi_b < 1.0e38f) tn = 0.5f * lo_b + 0.5f * hi_b;
        else if (cl > 64) { tn = tau2 + step; step *= 2.f; }
        else              { tn = tau2 - step; step *= 2.f; }
      }
      tau2 = tn;
    }
    if (found) {
      // wave-private compaction via shuffle prefix into cand[wv]
      int mycnt = 0;
#pragma unroll
      for (int jj = 0; jj < 32; ++jj) mycnt += (v[jj] > tau2) ? 1 : 0;
      int pre = mycnt;
#pragma unroll
      for (int off = 1; off < 64; off <<= 1) {
        int o = __shfl_up(pre, off, 64);
        if (lane >= off) pre += o;
      }
      int base = pre - mycnt;
      int tot = __shfl(pre, 63, 64);
      int pos = base;
#pragma unroll
      for (int jj = 0; jj < 32; ++jj) {
        if (v[jj] > tau2) {
          int col = ((jj >> 2) << 8) + lane * 4 + (jj & 3);
          cand[wv][pos] = make_key(v[jj], col);
          ++pos;
        }
      }
      myc = tot;                       // in [32,64]
    } else {
      // exact serial extraction (measure-zero path)
      unsigned alive = 0xFFFFFFFFu;
      for (int it = 0; it < TOPKK; ++it) {
        unsigned long long best = 0ull;
#pragma unroll
        for (int jj = 0; jj < 32; ++jj) {
          if ((alive >> jj) & 1u) {
            int col = ((jj >> 2) << 8) + lane * 4 + (jj & 3);
            unsigned long long kk = make_key(v[jj], col);
            if (kk > best) best = kk;
          }
        }
        unsigned long long b2 = best;
#pragma unroll
        for (int off = 1; off < 64; off <<= 1) {
          unsigned long long o = __shfl_xor(b2, off, 64);
          if (o > b2) b2 = o;
        }
        if (lane == it) keysel = b2;
        if (best == b2) {
#pragma unroll
          for (int jj = 0; jj < 32; ++jj) {
            int col = ((jj >> 2) << 8) + lane * 4 + (jj & 3);
            if (make_key(v[jj], col) == b2) alive &= ~(1u << jj);
          }
        }
      }
      myc = -1;                        // keysel already holds sorted top-32
    }
  }
  __syncthreads();   // fallback cand writes visible

  unsigned long long key;
  if (myc >= 0) {
    if (myc <= 64) {
      key = (lane < myc) ? cand[wv][lane] : 0ull;
      bitonic64_desc(key, lane);
    } else {
      key = cand[wv][lane];
      bitonic64_desc(key, lane);
      if (lane >= 32) { int idx = 64 + (lane - 32); key = (idx < myc) ? cand[wv][idx] : 0ull; }
      bitonic64_desc(key, lane);
    }
  } else {
    key = keysel;
  }

  // ---- softmax + dropout + renorm (verified r3/r4) ----
  float val; int col;
  decode_key(key, val, col);
  float m = __shfl(val, 0, 64);
  float e = (lane < TOPKK) ? expf(val - m) : 0.f;
  float s1 = e;
#pragma unroll
  for (int off = 1; off < 64; off <<= 1) s1 += __shfl_xor(s1, off, 64);
  float a1 = e / fmaxf(s1, 1e-6f);

  float a2 = 0.f;
  if (lane < TOPKK) {
    unsigned flat = (unsigned)g * 2048u + (unsigned)col;
    unsigned bits = threefry_bits(flat);
    float u = __uint_as_float((bits >> 9) | 0x3f800000u) - 1.0f;
    if (u <= 0.9f) a2 = a1 * (1.f / 0.9f);
  }
  float s2 = a2;
#pragma unroll
  for (int off = 1; off < 64; off <<= 1) s2 += __shfl_xor(s2, off, 64);
  float av = a2 / fmaxf(s2, 1e-6f);

  // ---- materialize A row via LDS rowbuf (verified r4/r6) ----
#pragma unroll
  for (int jj = 0; jj < 8; ++jj)
    *(float4*)&rowbuf[wv][jj * 256 + lane * 4] = make_float4(0.f, 0.f, 0.f, 0.f);
  __syncthreads();
  if (lane < TOPKK) rowbuf[wv][col] = av;
  __syncthreads();
  float* Arow = out + (size_t)g * NN;
#pragma unroll
  for (int jj = 0; jj < 8; ++jj)
    *(float4*)(Arow + jj * 256 + lane * 4) = *(float4*)&rowbuf[wv][jj * 256 + lane * 4];
}

extern "C" void kernel_launch(void* const* d_in, const int* in_sizes, int n_in,
                              void* d_out, int out_size, void* d_ws, size_t ws_size,
                              hipStream_t stream) {
  const float* X  = (const float*)d_in[0];
  const float* W  = (const float*)d_in[1];
  const float* Bm = (const float*)d_in[2];
  float* out = (float*)d_out;
  float* ws  = (float*)d_ws;   // ~5.5 MB used

  hipLaunchKernelGGL(rt_kernel, dim3(512), dim3(256), 0, stream, X, W, Bm, out, ws);
  hipLaunchKernelGGL(ga_kernel, dim3(64), dim3(256), 0, stream, out, ws);
  hipLaunchKernelGGL(gb_kernel, dim3(8), dim3(256), 0, stream, ws);
  hipLaunchKernelGGL(tau_kernel, dim3(4096), dim3(256), 0, stream, ws);
  hipLaunchKernelGGL(s_kernel, dim3(32, 32, 8), dim3(256), 0, stream, out, ws);
  hipLaunchKernelGGL(topk_kernel, dim3(4096), dim3(256), 0, stream, out, ws);
}

// Round 10
// 156.712 us; speedup vs baseline: 2.1178x; 1.2700x over previous
//
#include <hip/hip_runtime.h>
#include <math.h>

#define BATCH 8
#define NN 2048
#define DIN 256
#define RANK 64
#define TOPKK 32
#define CANDMAX 96

static constexpr size_t A_ELEMS = (size_t)BATCH * NN * NN;   // 33554432
static constexpr size_t S_OFF   = A_ELEMS;
static constexpr size_t R_OFF   = 2 * A_ELEMS;
static constexpr size_t NROWS   = (size_t)BATCH * NN;        // 16384

// ws layout (float offsets) — every word rewritten before read, every launch
static constexpr size_t T_OFF      = 0;                      // T[16384][64]
static constexpr size_t STAT_OFF   = 1048576;                // {sum,sumsq}[16384][32]
static constexpr size_t TAU_OFF    = STAT_OFF + NROWS * 64;  // tau[16384]
static constexpr size_t STATUS_OFF = TAU_OFF + NROWS;        // int[16384]
// total ≈ 8.5 MB

#define NEG_INF (-__builtin_inff())

// ---------------- threefry2x32, JAX partitionable counter-mode (verified r3) ----------------
__device__ __forceinline__ unsigned rotl32(unsigned x, int d) {
  return (x << d) | (x >> (32 - d));
}

__device__ unsigned threefry_bits(unsigned flat) {
  const unsigned ks0 = 0u, ks1 = 42u, ks2 = 0u ^ 42u ^ 0x1BD11BDAu;
  unsigned x0 = 0u + ks0;
  unsigned x1 = flat + ks1;
#define TF_ROUND(r) { x0 += x1; x1 = rotl32(x1, r); x1 ^= x0; }
  TF_ROUND(13) TF_ROUND(15) TF_ROUND(26) TF_ROUND(6)
  x0 += ks1; x1 += ks2 + 1u;
  TF_ROUND(17) TF_ROUND(29) TF_ROUND(16) TF_ROUND(24)
  x0 += ks2; x1 += ks0 + 2u;
  TF_ROUND(13) TF_ROUND(15) TF_ROUND(26) TF_ROUND(6)
  x0 += ks0; x1 += ks1 + 3u;
  TF_ROUND(17) TF_ROUND(29) TF_ROUND(16) TF_ROUND(24)
  x0 += ks1; x1 += ks2 + 4u;
  TF_ROUND(13) TF_ROUND(15) TF_ROUND(26) TF_ROUND(6)
  x0 += ks2; x1 += ks0 + 5u;
#undef TF_ROUND
  return x0 ^ x1;
}

__device__ __forceinline__ unsigned long long make_key(float v, int col) {
  unsigned u = __float_as_uint(v);
  u = (u & 0x80000000u) ? ~u : (u | 0x80000000u);
  return ((unsigned long long)u << 32) | (unsigned)(~col);
}

__device__ __forceinline__ void decode_key(unsigned long long key, float& val, int& col) {
  unsigned hi = (unsigned)(key >> 32);
  unsigned ub = (hi & 0x80000000u) ? (hi ^ 0x80000000u) : ~hi;
  val = __uint_as_float(ub);
  col = (int)(~(unsigned)key) & (NN - 1);
}

// lane MUST be the within-wave lane id (threadIdx.x & 63) (r5 bug)
__device__ __forceinline__ void bitonic64_desc(unsigned long long& key, int lane) {
#pragma unroll
  for (int k = 2; k <= 64; k <<= 1) {
#pragma unroll
    for (int j = k >> 1; j >= 1; j >>= 1) {
      unsigned long long o = __shfl_xor(key, j, 64);
      bool lower = (lane & j) == 0;
      bool desc  = (lane & k) == 0;
      bool takeMax = (lower == desc);
      bool kgo = key > o;
      key = (takeMax == kgo) ? key : o;
    }
  }
}

// softmax + dropout + renorm + direct A-row write (common epilogue)
__device__ __forceinline__ void epilogue_write(float* __restrict__ out,
                                               unsigned long long key,
                                               int g, int lane) {
  float val; int col;
  decode_key(key, val, col);
  float m = __shfl(val, 0, 64);
  float e = (lane < TOPKK) ? expf(val - m) : 0.f;
  float s1 = e;
#pragma unroll
  for (int off = 1; off < 64; off <<= 1) s1 += __shfl_xor(s1, off, 64);
  float a1 = e / fmaxf(s1, 1e-6f);

  float a2 = 0.f;
  if (lane < TOPKK) {
    unsigned flat = (unsigned)g * 2048u + (unsigned)col;
    unsigned bits = threefry_bits(flat);
    float u = __uint_as_float((bits >> 9) | 0x3f800000u) - 1.0f;
    if (u <= 0.9f) a2 = a1 * (1.f / 0.9f);
  }
  float s2 = a2;
#pragma unroll
  for (int off = 1; off < 64; off <<= 1) s2 += __shfl_xor(s2, off, 64);
  float av = a2 / fmaxf(s2, 1e-6f);

  float* Arow = out + (size_t)g * NN;
  float4 z = make_float4(0.f, 0.f, 0.f, 0.f);
#pragma unroll
  for (int jj = 0; jj < 8; ++jj)
    *(float4*)(Arow + jj * 256 + lane * 4) = z;
  asm volatile("s_waitcnt vmcnt(0)" ::: "memory");  // zeros retired before scatter
  if (lane < TOPKK) Arow[col] = av;
}

// ---------------- kernel 1: R = X*W -> out; T = (R*B)/8 -> ws (verified r4/r8) ----------------
__global__ __launch_bounds__(256) void rt_kernel(const float* __restrict__ X,
                                                 const float* __restrict__ W,
                                                 const float* __restrict__ Bm,
                                                 float* __restrict__ out,
                                                 float* __restrict__ ws) {
  __shared__ float Xs[32][256];
  __shared__ float Bs[64][64];
  __shared__ float Rs[32][64];
  const int t = threadIdx.x;
  const int blk = blockIdx.x;
  const int b  = blk >> 6;
  const int rb = blk & 63;
  const float* Xb = X + ((size_t)b * NN + (size_t)rb * 32) * DIN;

#pragma unroll
  for (int it = 0; it < 8; ++it) {
    int flat = it * 1024 + t * 4;
    *(float4*)&Xs[flat >> 8][flat & 255] = *(const float4*)(Xb + flat);
  }
#pragma unroll
  for (int it = 0; it < 4; ++it) {
    int flat = it * 1024 + t * 4;
    *(float4*)&Bs[flat >> 6][flat & 63] = *(const float4*)(Bm + flat);
  }
  __syncthreads();

  const int j = t & 63, rg = t >> 6;
  float acc[8] = {0.f, 0.f, 0.f, 0.f, 0.f, 0.f, 0.f, 0.f};
  for (int k = 0; k < DIN; k += 4) {
    float w0 = W[(k + 0) * RANK + j];
    float w1 = W[(k + 1) * RANK + j];
    float w2 = W[(k + 2) * RANK + j];
    float w3 = W[(k + 3) * RANK + j];
#pragma unroll
    for (int ii = 0; ii < 8; ++ii) {
      float4 xv = *(const float4*)&Xs[rg * 8 + ii][k];
      acc[ii] += xv.x * w0 + xv.y * w1 + xv.z * w2 + xv.w * w3;
    }
  }
  const size_t grow0 = (size_t)b * NN + (size_t)rb * 32;
  float* Rout = out + R_OFF + grow0 * RANK;
#pragma unroll
  for (int ii = 0; ii < 8; ++ii) {
    Rout[(size_t)(rg * 8 + ii) * RANK + j] = acc[ii];
    Rs[rg * 8 + ii][j] = acc[ii];
  }
  __syncthreads();

  float acc2[8] = {0.f, 0.f, 0.f, 0.f, 0.f, 0.f, 0.f, 0.f};
  for (int r = 0; r < RANK; r += 4) {
    float b0 = Bs[r + 0][j];
    float b1 = Bs[r + 1][j];
    float b2 = Bs[r + 2][j];
    float b3 = Bs[r + 3][j];
#pragma unroll
    for (int ii = 0; ii < 8; ++ii) {
      float4 rv = *(const float4*)&Rs[rg * 8 + ii][r];
      acc2[ii] += rv.x * b0 + rv.y * b1 + rv.z * b2 + rv.w * b3;
    }
  }
  float* Tout = ws + T_OFF + grow0 * RANK;
#pragma unroll
  for (int ii = 0; ii < 8; ++ii)
    Tout[(size_t)(rg * 8 + ii) * RANK + j] = acc2[ii] * 0.125f;
}

// ---------------- kernel 2: S = T * R^T (verified r4 tiling) + per-row stat partials ----------------
__global__ __launch_bounds__(256) void s_stat_kernel(float* __restrict__ out,
                                                     float* __restrict__ ws) {
  __shared__ float Ts[64][68];
  __shared__ float Rs[64][68];
  const int t = threadIdx.x;
  const int bx = blockIdx.x;  // col tile
  const int by = blockIdx.y;  // row tile
  const int bz = blockIdx.z;  // batch
  const float* Tg = ws + T_OFF + ((size_t)bz * NN + (size_t)by * 64) * RANK;
  const float* Rg = out + R_OFF + ((size_t)bz * NN + (size_t)bx * 64) * RANK;

#pragma unroll
  for (int it = 0; it < 4; ++it) {
    int flat = it * 1024 + t * 4;
    int r = flat >> 6, c = flat & 63;
    *(float4*)&Ts[r][c] = *(const float4*)(Tg + flat);
    *(float4*)&Rs[r][c] = *(const float4*)(Rg + flat);
  }
  __syncthreads();

  const int tx = t & 15, ty = t >> 4;
  float acc[4][4];
#pragma unroll
  for (int ii = 0; ii < 4; ++ii)
#pragma unroll
    for (int jj = 0; jj < 4; ++jj) acc[ii][jj] = 0.f;

  for (int k = 0; k < 64; k += 4) {
    float4 a[4], bb[4];
#pragma unroll
    for (int ii = 0; ii < 4; ++ii) a[ii] = *(const float4*)&Ts[ty + 16 * ii][k];
#pragma unroll
    for (int jj = 0; jj < 4; ++jj) bb[jj] = *(const float4*)&Rs[tx + 16 * jj][k];
#pragma unroll
    for (int ii = 0; ii < 4; ++ii)
#pragma unroll
      for (int jj = 0; jj < 4; ++jj)
        acc[ii][jj] += a[ii].x * bb[jj].x + a[ii].y * bb[jj].y +
                       a[ii].z * bb[jj].z + a[ii].w * bb[jj].w;
  }

  float* Sb = out + S_OFF + (size_t)bz * NN * NN;
#pragma unroll
  for (int ii = 0; ii < 4; ++ii) {
    int n = by * 64 + ty + 16 * ii;
#pragma unroll
    for (int jj = 0; jj < 4; ++jj) {
      int m = bx * 64 + tx + 16 * jj;
      Sb[(size_t)n * NN + m] = acc[ii][jj];
    }
  }

  // per-row partial {sum, sumsq} over this block's 64 cols; 16-lane shuffle reduce
#pragma unroll
  for (int ii = 0; ii < 4; ++ii) {
    float sp = 0.f, ssp = 0.f;
#pragma unroll
    for (int jj = 0; jj < 4; ++jj) {
      sp += acc[ii][jj];
      ssp = fmaf(acc[ii][jj], acc[ii][jj], ssp);
    }
#pragma unroll
    for (int off = 1; off < 16; off <<= 1) {   // stays within the 16-lane tx group
      sp  += __shfl_xor(sp, off, 64);
      ssp += __shfl_xor(ssp, off, 64);
    }
    if (tx == 0) {
      int n = by * 64 + ty + 16 * ii;
      size_t g = (size_t)bz * NN + n;
      float2 st = make_float2(sp, ssp);
      *(float2*)&ws[STAT_OFF + (g * 32 + bx) * 2] = st;
    }
  }
}

// ---------------- kernel 3: deterministic stat reduce -> tau ----------------
__global__ __launch_bounds__(256) void tau2_kernel(float* __restrict__ ws) {
  const int g = blockIdx.x * 256 + threadIdx.x;   // 64 blocks x 256
  float s = 0.f, ss = 0.f;
  const float* st = ws + STAT_OFF + (size_t)g * 64;
#pragma unroll
  for (int i = 0; i < 32; ++i) {
    float2 p = *(const float2*)&st[i * 2];
    s += p.x; ss += p.y;
  }
  float mu = s * (1.f / 2048.f);
  float sigma = sqrtf(fmaxf(ss * (1.f / 2048.f) - mu * mu, 1e-12f));
  ws[TAU_OFF + g] = mu + 1.8627f * sigma;         // target ~64 candidates
}

// ---------------- kernel 4: lean topk: ballot screen -> sort -> epilogue; status for fallback ----------------
__global__ __launch_bounds__(256) void topk_kernel(float* __restrict__ out,
                                                   float* __restrict__ ws) {
  __shared__ unsigned long long cand[4][CANDMAX];  // 3 KB only
  const int t = threadIdx.x;
  const int wv = t >> 6, lane = t & 63;
  const int g = blockIdx.x * 4 + wv;
  const int n = g & (NN - 1);
  const float tau = ws[TAU_OFF + g];

  const float* row = out + S_OFF + (size_t)g * NN;
  float v[32];
#pragma unroll
  for (int jj = 0; jj < 8; ++jj) {
    float4 f = *(const float4*)(row + jj * 256 + lane * 4);
    v[jj * 4 + 0] = f.x; v[jj * 4 + 1] = f.y;
    v[jj * 4 + 2] = f.z; v[jj * 4 + 3] = f.w;
  }

  // ---- ballot-prefix screen (no atomics); positions dense & unique ----
  const unsigned long long below = (1ull << lane) - 1ull;
  int base = 0;
#pragma unroll
  for (int jj = 0; jj < 32; ++jj) {
    int col = ((jj >> 2) << 8) + lane * 4 + (jj & 3);
    bool pred = (col != n) && (v[jj] > tau);
    unsigned long long mask = __ballot(pred);
    if (pred) {
      int pos = base + __popcll(mask & below);
      if (pos < CANDMAX) cand[wv][pos] = make_key(v[jj], col);
    }
    base += __popcll(mask);
  }
  const int c = base;                              // wave-uniform

  int* status = (int*)(ws + STATUS_OFF);
  if (c < TOPKK || c > CANDMAX) {                  // rare: defer to fallback kernel
    if (lane == 0) status[g] = 0;
    return;
  }
  if (lane == 0) status[g] = 1;

  __builtin_amdgcn_s_waitcnt(0);                   // LDS writes visible to own wave

  unsigned long long key;
  if (c <= 64) {
    key = (lane < c) ? cand[wv][lane] : 0ull;
    bitonic64_desc(key, lane);
  } else {
    key = cand[wv][lane];
    bitonic64_desc(key, lane);
    if (lane >= 32) { int idx = 64 + (lane - 32); key = (idx < c) ? cand[wv][idx] : 0ull; }
    bitonic64_desc(key, lane);
  }

  epilogue_write(out, key, g, lane);
}

// ---------------- kernel 5: fallback for rows with count outside [32,96] (expected ~1 row) ----------------
__global__ __launch_bounds__(256) void fb_kernel(float* __restrict__ out,
                                                 const float* __restrict__ ws) {
  __shared__ unsigned long long cand[4][64];
  const int t = threadIdx.x;
  const int wv = t >> 6, lane = t & 63;
  const int* status = (const int*)(ws + STATUS_OFF);

  for (int g = blockIdx.x * 4 + wv; g < (int)NROWS; g += 256 * 4) {
    if (status[g]) continue;
    const int n = g & (NN - 1);
    const float* row = out + S_OFF + (size_t)g * NN;
    float v[32];
#pragma unroll
    for (int jj = 0; jj < 8; ++jj) {
      float4 f = *(const float4*)(row + jj * 256 + lane * 4);
      v[jj * 4 + 0] = f.x; v[jj * 4 + 1] = f.y;
      v[jj * 4 + 2] = f.z; v[jj * 4 + 3] = f.w;
    }
    float s = 0.f, ss = 0.f;
#pragma unroll
    for (int jj = 0; jj < 32; ++jj) { s += v[jj]; ss = fmaf(v[jj], v[jj], ss); }
#pragma unroll
    for (int off = 1; off < 64; off <<= 1) {
      s += __shfl_xor(s, off, 64); ss += __shfl_xor(ss, off, 64);
    }
    const float mu = s * (1.f / 2048.f);
    const float sigma = sqrtf(fmaxf(ss * (1.f / 2048.f) - mu * mu, 1e-12f));
    {
      int d = n - lane * 4;
      if (d >= 0 && d < NN && (d & 255) < 4) v[((d >> 8) << 2) | (d & 3)] = NEG_INF;
    }
    float tau2 = mu + 2.0641f * sigma;
    float lo_b = -3.0e38f, hi_b = 3.0e38f;
    float step = sigma + 1e-20f;
    bool found = false;
    for (int it = 0; it < 40; ++it) {
      int cl = 0;
#pragma unroll
      for (int jj = 0; jj < 32; ++jj) cl += (v[jj] > tau2) ? 1 : 0;
#pragma unroll
      for (int off = 1; off < 64; off <<= 1) cl += __shfl_xor(cl, off, 64);
      if (cl >= TOPKK && cl <= 64) { found = true; break; }
      if (cl > 64) lo_b = fmaxf(lo_b, tau2); else hi_b = fminf(hi_b, tau2);
      float tn = 0.f; bool ok = false;
      if (it < 6) {
        float pp = fminf(fmaxf((float)cl, 1.f) * (1.f / 2048.f), 0.5f);
        float tt = sqrtf(-2.f * logf(pp));
        float zc = tt - (2.30753f + 0.27061f * tt) /
                        (1.f + tt * (0.99229f + 0.04481f * tt));
        zc = fmaxf(zc, 0.05f);
        tn = mu + 2.0641f * ((tau2 - mu) / zc);
        ok = (tn > lo_b && tn < hi_b);
      }
      if (!ok) {
        if (lo_b > -1.0e38f && hi_b < 1.0e38f) tn = 0.5f * lo_b + 0.5f * hi_b;
        else if (cl > 64) { tn = tau2 + step; step *= 2.f; }
        else              { tn = tau2 - step; step *= 2.f; }
      }
      tau2 = tn;
    }

    unsigned long long key = 0ull;
    if (found) {
      const unsigned long long below = (1ull << lane) - 1ull;
      int base = 0;
#pragma unroll
      for (int jj = 0; jj < 32; ++jj) {
        int col = ((jj >> 2) << 8) + lane * 4 + (jj & 3);
        bool pred = (v[jj] > tau2);
        unsigned long long mask = __ballot(pred);
        if (pred) cand[wv][base + __popcll(mask & below)] = make_key(v[jj], col);
        base += __popcll(mask);
      }
      __builtin_amdgcn_s_waitcnt(0);
      key = (lane < base) ? cand[wv][lane] : 0ull;
      bitonic64_desc(key, lane);
    } else {
      // exact serial extraction (measure-zero path)
      unsigned alive = 0xFFFFFFFFu;
      unsigned long long keysel = 0ull;
      for (int it = 0; it < TOPKK; ++it) {
        unsigned long long best = 0ull;
#pragma unroll
        for (int jj = 0; jj < 32; ++jj) {
          if ((alive >> jj) & 1u) {
            int col = ((jj >> 2) << 8) + lane * 4 + (jj & 3);
            unsigned long long kk = make_key(v[jj], col);
            if (kk > best) best = kk;
          }
        }
        unsigned long long b2 = best;
#pragma unroll
        for (int off = 1; off < 64; off <<= 1) {
          unsigned long long o = __shfl_xor(b2, off, 64);
          if (o > b2) b2 = o;
        }
        if (lane == it) keysel = b2;
        if (best == b2) {
#pragma unroll
          for (int jj = 0; jj < 32; ++jj) {
            int col = ((jj >> 2) << 8) + lane * 4 + (jj & 3);
            if (make_key(v[jj], col) == b2) alive &= ~(1u << jj);
          }
        }
      }
      key = keysel;
    }

    epilogue_write(out, key, g, lane);
  }
}

extern "C" void kernel_launch(void* const* d_in, const int* in_sizes, int n_in,
                              void* d_out, int out_size, void* d_ws, size_t ws_size,
                              hipStream_t stream) {
  const float* X  = (const float*)d_in[0];
  const float* W  = (const float*)d_in[1];
  const float* Bm = (const float*)d_in[2];
  float* out = (float*)d_out;
  float* ws  = (float*)d_ws;   // ~8.5 MB used

  hipLaunchKernelGGL(rt_kernel, dim3(512), dim3(256), 0, stream, X, W, Bm, out, ws);
  hipLaunchKernelGGL(s_stat_kernel, dim3(32, 32, 8), dim3(256), 0, stream, out, ws);
  hipLaunchKernelGGL(tau2_kernel, dim3(64), dim3(256), 0, stream, ws);
  hipLaunchKernelGGL(topk_kernel, dim3(4096), dim3(256), 0, stream, out, ws);
  hipLaunchKernelGGL(fb_kernel, dim3(256), dim3(256), 0, stream, out, ws);
}